// Round 1
// baseline (212.673 us; speedup 1.0000x reference)
//
#include <hip/hip_runtime.h>

#define BATCH 8
#define S_LEN 2048
#define DDIM 512
#define UDIM 512
#define WIN_L 128
#define WIN_R 128

typedef _Float16 f16;
typedef __attribute__((ext_vector_type(8))) _Float16 f16x8;
typedef __attribute__((ext_vector_type(4))) _Float16 f16x4;
typedef __attribute__((ext_vector_type(4))) float f32x4;

__device__ __forceinline__ void gload_lds16(const void* g, void* l) {
  __builtin_amdgcn_global_load_lds((const __attribute__((address_space(1))) void*)g,
                                   (__attribute__((address_space(3))) void*)l, 16, 0, 0);
}

// ---------------- cast x (fp32) -> f16 ----------------
__global__ void cast_f32_f16(const float* __restrict__ in, f16* __restrict__ out, int n) {
  int i = (blockIdx.x * blockDim.x + threadIdx.x) * 4;
  if (i < n) {
    float4 v = *(const float4*)(in + i);
    f16x4 o;
    o[0] = (f16)v.x; o[1] = (f16)v.y; o[2] = (f16)v.z; o[3] = (f16)v.w;
    *(f16x4*)(out + i) = o;
  }
}

// ---------------- transpose W [D][U] fp32 -> WT [U][D] f16 (3 matrices) ----------------
__global__ void transpose_w(const float* __restrict__ Wq, const float* __restrict__ Wk,
                            const float* __restrict__ Wv, f16* __restrict__ WT) {
  const float* W = blockIdx.z == 0 ? Wq : (blockIdx.z == 1 ? Wk : Wv);
  f16* WTz = WT + (size_t)blockIdx.z * DDIM * UDIM;
  __shared__ float t[32][33];
  int tx = threadIdx.x & 31, ty = threadIdx.x >> 5;  // 32 x 8
  int n0 = blockIdx.x * 32, k0 = blockIdx.y * 32;
  for (int i = 0; i < 4; i++) {
    int r = ty * 4 + i;  // k offset
    t[r][tx] = W[(size_t)(k0 + r) * UDIM + n0 + tx];
  }
  __syncthreads();
  for (int i = 0; i < 4; i++) {
    int r = ty * 4 + i;  // n offset
    WTz[(size_t)(n0 + r) * DDIM + k0 + tx] = (f16)t[tx][r];
  }
}

// ---------------- transpose V [b][s][u] -> VT [b][u][s] (f16) ----------------
__global__ void transpose_v(const f16* __restrict__ V, f16* __restrict__ VT) {
  __shared__ f16 t[32][34];
  int b = blockIdx.z;
  int u0 = blockIdx.x * 32, s0 = blockIdx.y * 32;
  int tx = threadIdx.x & 31, ty = threadIdx.x >> 5;
  const f16* Vb = V + (size_t)b * S_LEN * UDIM;
  f16* VTb = VT + (size_t)b * UDIM * S_LEN;
  for (int i = 0; i < 4; i++) {
    int r = ty * 4 + i;  // s offset
    t[r][tx] = Vb[(size_t)(s0 + r) * UDIM + u0 + tx];
  }
  __syncthreads();
  for (int i = 0; i < 4; i++) {
    int r = ty * 4 + i;  // u offset
    VTb[(size_t)(u0 + r) * S_LEN + s0 + tx] = t[tx][r];
  }
}

// ---------------- QKV GEMM: [16384 x 512] = X[16384 x 512] * W[512 x 512] + b ----------------
// m97 structure: 128x128 tile, 4 waves each 64x64, BK=32, global_load_lds w16.
__global__ __launch_bounds__(256, 2) void gemm_qkv(
    const f16* __restrict__ X, const f16* __restrict__ WT,
    const float* __restrict__ bq, const float* __restrict__ bk, const float* __restrict__ bv,
    f16* __restrict__ QKV) {
  int z = blockIdx.z;
  const f16* WTz = WT + (size_t)z * DDIM * UDIM;   // [U][D] layout
  const float* bias = z == 0 ? bq : (z == 1 ? bk : bv);
  f16* out = QKV + (size_t)z * (BATCH * S_LEN) * UDIM;

  __shared__ f16 Al[128 * 32];
  __shared__ f16 Bl[128 * 32];

  int tid = threadIdx.x, wv = tid >> 6, ln = tid & 63;
  int m0 = blockIdx.x * 128, n0 = blockIdx.y * 128;
  int wm = (wv >> 1) * 64, wn = (wv & 1) * 64;
  int lm = ln & 15, lq = ln >> 4;
  int srow = ln >> 2, scol = (ln & 3) * 8;

  f32x4 acc[4][4];
  for (int mt = 0; mt < 4; mt++)
    for (int nt = 0; nt < 4; nt++)
      for (int r = 0; r < 4; r++) acc[mt][nt][r] = 0.f;

  for (int k0 = 0; k0 < DDIM; k0 += 32) {
    for (int half = 0; half < 2; half++) {
      int r0 = half * 64 + wv * 16;  // wave-uniform
      gload_lds16(X + (size_t)(m0 + r0 + srow) * DDIM + k0 + scol, &Al[r0 * 32]);
      gload_lds16(WTz + (size_t)(n0 + r0 + srow) * DDIM + k0 + scol, &Bl[r0 * 32]);
    }
    __syncthreads();
    f16x8 af[4], bfr[4];
    for (int mt = 0; mt < 4; mt++) af[mt] = *(const f16x8*)&Al[(wm + mt * 16 + lm) * 32 + lq * 8];
    for (int nt = 0; nt < 4; nt++) bfr[nt] = *(const f16x8*)&Bl[(wn + nt * 16 + lm) * 32 + lq * 8];
    for (int mt = 0; mt < 4; mt++)
      for (int nt = 0; nt < 4; nt++)
        acc[mt][nt] = __builtin_amdgcn_mfma_f32_16x16x32_f16(af[mt], bfr[nt], acc[mt][nt], 0, 0, 0);
    __syncthreads();
  }

  for (int mt = 0; mt < 4; mt++)
    for (int nt = 0; nt < 4; nt++) {
      int col = n0 + wn + nt * 16 + lm;
      float bv_ = bias[col];
      for (int r = 0; r < 4; r++) {
        int row = m0 + wm + mt * 16 + lq * 4 + r;
        out[(size_t)row * UDIM + col] = (f16)(acc[mt][nt][r] + bv_);
      }
    }
}

// ---------------- flash-style sliding-window attention ----------------
// grid (S/32, B), 256 threads. Q-tile 32 rows. Key blocks of 32 within [q0-128, q0+32+128).
__global__ __launch_bounds__(256, 2) void attn(
    const f16* __restrict__ Q, const f16* __restrict__ K, const f16* __restrict__ VT,
    float* __restrict__ out) {
  __shared__ f16 Kl[32 * 520];    // K block [32 keys][512 u], pitch padded (2-way max)
  __shared__ f16 Vl[512 * 40];    // VT block [512 u][32 keys], pitch padded
  __shared__ float Sb[32 * 33];   // scores fp32
  __shared__ f16 Pb[32 * 40];     // probabilities f16, A-operand layout source
  __shared__ float mrun[32], lrun[32], alph[32];

  int tid = threadIdx.x, wv = tid >> 6, ln = tid & 63;
  int lm = ln & 15, lq = ln >> 4;
  int b = blockIdx.y, q0 = blockIdx.x * 32;
  const size_t base = (size_t)b * S_LEN;

  if (tid < 32) { mrun[tid] = -INFINITY; lrun[tid] = 0.f; }

  // Q fragments in registers: A-operand for this wave's S-tile row half (smt)
  int smt = wv >> 1, snt = wv & 1;
  f16x8 qf[16];
  {
    const f16* qrow = Q + (base + q0 + smt * 16 + lm) * (size_t)DDIM + lq * 8;
    for (int kk = 0; kk < 16; kk++) qf[kk] = *(const f16x8*)(qrow + kk * 32);
  }
  f32x4 oacc[2][8];
  for (int mt = 0; mt < 2; mt++)
    for (int nt = 0; nt < 8; nt++)
      for (int r = 0; r < 4; r++) oacc[mt][nt][r] = 0.f;

  int jlo = q0 - WIN_L; if (jlo < 0) jlo = 0;
  int jhi = q0 + 32 + WIN_R; if (jhi > S_LEN) jhi = S_LEN;

  for (int j0 = jlo; j0 < jhi; j0 += 32) {
    // stage K block (32 x 512) and VT block (512 x 32), manual for padded pitch
    for (int i = 0; i < 8; i++) {
      int c = tid + 256 * i;
      int kr = c >> 6, kc = (c & 63) * 8;
      *(uint4*)&Kl[kr * 520 + kc] = *(const uint4*)(K + (base + j0 + kr) * (size_t)DDIM + kc);
    }
    for (int i = 0; i < 8; i++) {
      int c = tid + 256 * i;
      int u = c >> 2, cc = (c & 3) * 8;
      *(uint4*)&Vl[u * 40 + cc] = *(const uint4*)(VT + ((size_t)b * UDIM + u) * S_LEN + j0 + cc);
    }
    __syncthreads();

    // S-tile: wave (smt,snt) computes 16x16 quarter of 32x32 scores
    f32x4 sacc;
    for (int r = 0; r < 4; r++) sacc[r] = 0.f;
    for (int kk = 0; kk < 16; kk++) {
      f16x8 bfr = *(const f16x8*)&Kl[(snt * 16 + lm) * 520 + kk * 32 + lq * 8];
      sacc = __builtin_amdgcn_mfma_f32_16x16x32_f16(qf[kk], bfr, sacc, 0, 0, 0);
    }
    const float scale = 0.044194173824159216f;  // 1/sqrt(512)
    for (int r = 0; r < 4; r++) {
      int row = smt * 16 + lq * 4 + r;
      int col = snt * 16 + lm;
      int qi = q0 + row, kj = j0 + col;
      float v = sacc[r] * scale;
      if (kj < qi - WIN_L || kj > qi + WIN_R) v = -INFINITY;
      Sb[row * 33 + col] = v;
    }
    __syncthreads();

    // online softmax: 8 threads per row
    {
      int r = tid >> 3, l8 = tid & 7;
      float sv[4];
      float mx = -INFINITY;
      for (int cc = 0; cc < 4; cc++) {
        sv[cc] = Sb[r * 33 + l8 * 4 + cc];
        mx = fmaxf(mx, sv[cc]);
      }
      mx = fmaxf(mx, __shfl_xor(mx, 1));
      mx = fmaxf(mx, __shfl_xor(mx, 2));
      mx = fmaxf(mx, __shfl_xor(mx, 4));
      float mold = mrun[r];
      float mnew = fmaxf(mold, mx);
      float a = __expf(mold - mnew);
      float sum = 0.f;
      for (int cc = 0; cc < 4; cc++) {
        float p = __expf(sv[cc] - mnew);
        sum += p;
        Pb[r * 40 + l8 * 4 + cc] = (f16)p;
      }
      sum += __shfl_xor(sum, 1);
      sum += __shfl_xor(sum, 2);
      sum += __shfl_xor(sum, 4);
      if (l8 == 0) {
        lrun[r] = a * lrun[r] + sum;
        mrun[r] = mnew;
        alph[r] = a;
      }
    }
    __syncthreads();

    // rescale O and accumulate P*V; wave owns u-range [wv*128, wv*128+128)
    {
      float al[2][4];
      for (int mt = 0; mt < 2; mt++)
        for (int r = 0; r < 4; r++) al[mt][r] = alph[mt * 16 + lq * 4 + r];
      for (int mt = 0; mt < 2; mt++)
        for (int nt = 0; nt < 8; nt++)
          for (int r = 0; r < 4; r++) oacc[mt][nt][r] *= al[mt][r];
      f16x8 pf[2];
      for (int mt = 0; mt < 2; mt++)
        pf[mt] = *(const f16x8*)&Pb[(mt * 16 + lm) * 40 + lq * 8];
      for (int nt = 0; nt < 8; nt++) {
        f16x8 bfr = *(const f16x8*)&Vl[(wv * 128 + nt * 16 + lm) * 40 + lq * 8];
        oacc[0][nt] = __builtin_amdgcn_mfma_f32_16x16x32_f16(pf[0], bfr, oacc[0][nt], 0, 0, 0);
        oacc[1][nt] = __builtin_amdgcn_mfma_f32_16x16x32_f16(pf[1], bfr, oacc[1][nt], 0, 0, 0);
      }
    }
    __syncthreads();
  }

  // epilogue: O /= l, store fp32
  {
    float linv[2][4];
    for (int mt = 0; mt < 2; mt++)
      for (int r = 0; r < 4; r++) linv[mt][r] = 1.0f / lrun[mt * 16 + lq * 4 + r];
    for (int mt = 0; mt < 2; mt++)
      for (int nt = 0; nt < 8; nt++)
        for (int r = 0; r < 4; r++) {
          int row = q0 + mt * 16 + lq * 4 + r;
          int col = wv * 128 + nt * 16 + lm;
          out[(base + row) * (size_t)UDIM + col] = oacc[mt][nt][r] * linv[mt][r];
        }
  }
}

extern "C" void kernel_launch(void* const* d_in, const int* in_sizes, int n_in,
                              void* d_out, int out_size, void* d_ws, size_t ws_size,
                              hipStream_t stream) {
  const float* x  = (const float*)d_in[0];
  const float* Wq = (const float*)d_in[1];
  const float* Wk = (const float*)d_in[2];
  const float* Wv = (const float*)d_in[3];
  const float* bq = (const float*)d_in[4];
  const float* bk = (const float*)d_in[5];
  const float* bv = (const float*)d_in[6];
  float* out = (float*)d_out;

  char* ws = (char*)d_ws;
  const size_t XB_BYTES  = (size_t)BATCH * S_LEN * DDIM * 2;       // 16.8 MB
  const size_t WT_BYTES  = (size_t)3 * DDIM * UDIM * 2;            // 1.5 MB
  const size_t QKV_BYTES = (size_t)3 * BATCH * S_LEN * UDIM * 2;   // 50.3 MB
  f16* xb  = (f16*)ws;
  f16* WT  = (f16*)(ws + XB_BYTES);
  f16* QKV = (f16*)(ws + XB_BYTES + WT_BYTES);
  f16* VT  = (f16*)(ws + XB_BYTES + WT_BYTES + QKV_BYTES);

  int n = BATCH * S_LEN * DDIM;
  cast_f32_f16<<<n / (256 * 4), 256, 0, stream>>>(x, xb, n);
  transpose_w<<<dim3(16, 16, 3), 256, 0, stream>>>(Wq, Wk, Wv, WT);
  gemm_qkv<<<dim3(128, 4, 3), 256, 0, stream>>>(xb, WT, bq, bk, bv, QKV);
  f16* Vmat = QKV + (size_t)2 * BATCH * S_LEN * UDIM;
  transpose_v<<<dim3(16, 64, 8), 256, 0, stream>>>(Vmat, VT);
  attn<<<dim3(S_LEN / 32, BATCH), 256, 0, stream>>>(QKV, QKV + (size_t)BATCH * S_LEN * UDIM, VT, out);
}

// Round 2
// 187.972 us; speedup vs baseline: 1.1314x; 1.1314x over previous
//
#include <hip/hip_runtime.h>

#define BATCH 8
#define S_LEN 2048
#define DDIM 512
#define UDIM 512
#define WIN_L 128
#define WIN_R 128

typedef _Float16 f16;
typedef __attribute__((ext_vector_type(8))) _Float16 f16x8;
typedef __attribute__((ext_vector_type(4))) _Float16 f16x4;
typedef __attribute__((ext_vector_type(4))) float f32x4;

__device__ __forceinline__ void gload_lds16(const void* g, void* l) {
  __builtin_amdgcn_global_load_lds((const __attribute__((address_space(1))) void*)g,
                                   (__attribute__((address_space(3))) void*)l, 16, 0, 0);
}

// ---------------- cast x (fp32) -> f16 ----------------
__global__ void cast_f32_f16(const float* __restrict__ in, f16* __restrict__ out, int n) {
  int i = (blockIdx.x * blockDim.x + threadIdx.x) * 4;
  if (i < n) {
    float4 v = *(const float4*)(in + i);
    f16x4 o;
    o[0] = (f16)v.x; o[1] = (f16)v.y; o[2] = (f16)v.z; o[3] = (f16)v.w;
    *(f16x4*)(out + i) = o;
  }
}

// ---------------- transpose W [D][U] fp32 -> WT [U][D] f16 (3 matrices) ----------------
__global__ void transpose_w(const float* __restrict__ Wq, const float* __restrict__ Wk,
                            const float* __restrict__ Wv, f16* __restrict__ WT) {
  const float* W = blockIdx.z == 0 ? Wq : (blockIdx.z == 1 ? Wk : Wv);
  f16* WTz = WT + (size_t)blockIdx.z * DDIM * UDIM;
  __shared__ float t[32][33];
  int tx = threadIdx.x & 31, ty = threadIdx.x >> 5;  // 32 x 8
  int n0 = blockIdx.x * 32, k0 = blockIdx.y * 32;
  for (int i = 0; i < 4; i++) {
    int r = ty * 4 + i;  // k offset
    t[r][tx] = W[(size_t)(k0 + r) * UDIM + n0 + tx];
  }
  __syncthreads();
  for (int i = 0; i < 4; i++) {
    int r = ty * 4 + i;  // n offset
    WTz[(size_t)(n0 + r) * DDIM + k0 + tx] = (f16)t[tx][r];
  }
}

// ---------------- QKV GEMM: [16384 x 512] = X[16384 x 512] * W[512 x 512] + b ----------------
// m97 structure: 128x128 tile, 4 waves each 64x64, BK=32, global_load_lds w16.
// z==2 (V) writes the TRANSPOSED output VT[b][u][s] directly (attention needs V^T).
__global__ __launch_bounds__(256, 2) void gemm_qkv(
    const f16* __restrict__ X, const f16* __restrict__ WT,
    const float* __restrict__ bq, const float* __restrict__ bk, const float* __restrict__ bv,
    f16* __restrict__ QKV, f16* __restrict__ VT) {
  int z = blockIdx.z;
  const f16* WTz = WT + (size_t)z * DDIM * UDIM;   // [U][D] layout
  const float* bias = z == 0 ? bq : (z == 1 ? bk : bv);
  f16* out = QKV + (size_t)z * (BATCH * S_LEN) * UDIM;

  __shared__ f16 Al[128 * 32];
  __shared__ f16 Bl[128 * 32];

  int tid = threadIdx.x, wv = tid >> 6, ln = tid & 63;
  int m0 = blockIdx.x * 128, n0 = blockIdx.y * 128;
  int wm = (wv >> 1) * 64, wn = (wv & 1) * 64;
  int lm = ln & 15, lq = ln >> 4;
  int srow = ln >> 2, scol = (ln & 3) * 8;

  f32x4 acc[4][4];
  for (int mt = 0; mt < 4; mt++)
    for (int nt = 0; nt < 4; nt++)
      for (int r = 0; r < 4; r++) acc[mt][nt][r] = 0.f;

  for (int k0 = 0; k0 < DDIM; k0 += 32) {
    for (int half = 0; half < 2; half++) {
      int r0 = half * 64 + wv * 16;  // wave-uniform
      gload_lds16(X + (size_t)(m0 + r0 + srow) * DDIM + k0 + scol, &Al[r0 * 32]);
      gload_lds16(WTz + (size_t)(n0 + r0 + srow) * DDIM + k0 + scol, &Bl[r0 * 32]);
    }
    __syncthreads();
    f16x8 af[4], bfr[4];
    for (int mt = 0; mt < 4; mt++) af[mt] = *(const f16x8*)&Al[(wm + mt * 16 + lm) * 32 + lq * 8];
    for (int nt = 0; nt < 4; nt++) bfr[nt] = *(const f16x8*)&Bl[(wn + nt * 16 + lm) * 32 + lq * 8];
    for (int mt = 0; mt < 4; mt++)
      for (int nt = 0; nt < 4; nt++)
        acc[mt][nt] = __builtin_amdgcn_mfma_f32_16x16x32_f16(af[mt], bfr[nt], acc[mt][nt], 0, 0, 0);
    __syncthreads();
  }

  if (z == 2) {
    // transposed epilogue: VT[b][u][s], 4 consecutive s per lane -> 8B vector stores
    for (int mt = 0; mt < 4; mt++)
      for (int nt = 0; nt < 4; nt++) {
        int col = n0 + wn + nt * 16 + lm;          // u
        float bv_ = bias[col];
        int row0 = m0 + wm + mt * 16 + lq * 4;     // global s index (r=0)
        int bb = row0 >> 11, ss = row0 & 2047;
        f16x4 o;
        for (int r = 0; r < 4; r++) o[r] = (f16)(acc[mt][nt][r] + bv_);
        *(f16x4*)&VT[((size_t)bb * UDIM + col) * S_LEN + ss] = o;
      }
  } else {
    for (int mt = 0; mt < 4; mt++)
      for (int nt = 0; nt < 4; nt++) {
        int col = n0 + wn + nt * 16 + lm;
        float bv_ = bias[col];
        for (int r = 0; r < 4; r++) {
          int row = m0 + wm + mt * 16 + lq * 4 + r;
          out[(size_t)row * UDIM + col] = (f16)(acc[mt][nt][r] + bv_);
        }
      }
  }
}

// ---------------- flash-style sliding-window attention, v2 ----------------
// grid (B, S/32): linear block id % 8 == batch -> batch pinned to one XCD, K/V window
// stays L2-resident. K and VT fragments loaded DIRECTLY from global (L2) -- no LDS
// staging, LDS only for S->P layout round-trip + softmax state. 2 barriers per step.
__global__ __launch_bounds__(256, 2) void attn(
    const f16* __restrict__ Q, const f16* __restrict__ K, const f16* __restrict__ VT,
    float* __restrict__ out) {
  __shared__ float Sb[32 * 33];   // scores fp32
  __shared__ f16 Pb[32 * 40];     // probabilities f16 (A-operand source)
  __shared__ float mrun[32], lrun[32], alph[32];

  int tid = threadIdx.x, wv = tid >> 6, ln = tid & 63;
  int lm = ln & 15, lq = ln >> 4;
  int b = blockIdx.x, q0 = blockIdx.y * 32;
  const size_t base = (size_t)b * S_LEN;

  if (tid < 32) { mrun[tid] = -INFINITY; lrun[tid] = 0.f; }

  // Q fragments in registers (A-operand), invariant across key blocks
  int smt = wv >> 1, snt = wv & 1;
  f16x8 qf[16];
  {
    const f16* qrow = Q + (base + q0 + smt * 16 + lm) * (size_t)DDIM + lq * 8;
    for (int kk = 0; kk < 16; kk++) qf[kk] = *(const f16x8*)(qrow + kk * 32);
  }
  f32x4 oacc[2][8];
  for (int mt = 0; mt < 2; mt++)
    for (int nt = 0; nt < 8; nt++)
      for (int r = 0; r < 4; r++) oacc[mt][nt][r] = 0.f;

  int jlo = q0 - WIN_L; if (jlo < 0) jlo = 0;
  int jhi = q0 + 32 + WIN_R; if (jhi > S_LEN) jhi = S_LEN;

  const f16* krow = K + (base + snt * 16 + lm) * (size_t)DDIM + lq * 8;
  const f16* vrow = VT + ((size_t)b * UDIM + wv * 128 + lm) * S_LEN + lq * 8;
  const float scale = 0.044194173824159216f;  // 1/sqrt(512)

  for (int j0 = jlo; j0 < jhi; j0 += 32) {
    // ---- S = Q K^T for this 32-key block; B-frags straight from global (L2) ----
    const f16* kp = krow + (size_t)j0 * DDIM;
    f32x4 sacc0, sacc1;
    for (int r = 0; r < 4; r++) { sacc0[r] = 0.f; sacc1[r] = 0.f; }
    for (int kk = 0; kk < 16; kk += 2) {
      f16x8 b0 = *(const f16x8*)(kp + kk * 32);
      f16x8 b1 = *(const f16x8*)(kp + (kk + 1) * 32);
      sacc0 = __builtin_amdgcn_mfma_f32_16x16x32_f16(qf[kk], b0, sacc0, 0, 0, 0);
      sacc1 = __builtin_amdgcn_mfma_f32_16x16x32_f16(qf[kk + 1], b1, sacc1, 0, 0, 0);
    }
    for (int r = 0; r < 4; r++) {
      int row = smt * 16 + lq * 4 + r;
      int col = snt * 16 + lm;
      int qi = q0 + row, kj = j0 + col;
      float v = (sacc0[r] + sacc1[r]) * scale;
      if (kj < qi - WIN_L || kj > qi + WIN_R) v = -INFINITY;
      Sb[row * 33 + col] = v;
    }
    __syncthreads();

    // ---- online softmax: 8 threads per row ----
    {
      int r = tid >> 3, l8 = tid & 7;
      float sv[4];
      float mx = -INFINITY;
      for (int cc = 0; cc < 4; cc++) {
        sv[cc] = Sb[r * 33 + l8 * 4 + cc];
        mx = fmaxf(mx, sv[cc]);
      }
      mx = fmaxf(mx, __shfl_xor(mx, 1));
      mx = fmaxf(mx, __shfl_xor(mx, 2));
      mx = fmaxf(mx, __shfl_xor(mx, 4));
      float mold = mrun[r];
      float mnew = fmaxf(mold, mx);
      float a = __expf(mold - mnew);
      float sum = 0.f;
      for (int cc = 0; cc < 4; cc++) {
        float p = __expf(sv[cc] - mnew);
        sum += p;
        Pb[r * 40 + l8 * 4 + cc] = (f16)p;
      }
      sum += __shfl_xor(sum, 1);
      sum += __shfl_xor(sum, 2);
      sum += __shfl_xor(sum, 4);
      if (l8 == 0) {
        lrun[r] = a * lrun[r] + sum;
        mrun[r] = mnew;
        alph[r] = a;
      }
    }
    __syncthreads();

    // ---- O = alpha*O + P V ; V B-frags straight from global (L2) ----
    {
      float al[2][4];
      for (int mt = 0; mt < 2; mt++)
        for (int r = 0; r < 4; r++) al[mt][r] = alph[mt * 16 + lq * 4 + r];
      for (int mt = 0; mt < 2; mt++)
        for (int nt = 0; nt < 8; nt++)
          for (int r = 0; r < 4; r++) oacc[mt][nt][r] *= al[mt][r];
      f16x8 pf[2];
      for (int mt = 0; mt < 2; mt++)
        pf[mt] = *(const f16x8*)&Pb[(mt * 16 + lm) * 40 + lq * 8];
      const f16* vp = vrow + j0;
      for (int nt = 0; nt < 8; nt++) {
        f16x8 bfr = *(const f16x8*)(vp + (size_t)nt * 16 * S_LEN);
        oacc[0][nt] = __builtin_amdgcn_mfma_f32_16x16x32_f16(pf[0], bfr, oacc[0][nt], 0, 0, 0);
        oacc[1][nt] = __builtin_amdgcn_mfma_f32_16x16x32_f16(pf[1], bfr, oacc[1][nt], 0, 0, 0);
      }
    }
    // no barrier needed here: next Sb write precedes barrier1, next Pb write follows it
  }

  // epilogue: O /= l, store fp32
  {
    float linv[2][4];
    for (int mt = 0; mt < 2; mt++)
      for (int r = 0; r < 4; r++) linv[mt][r] = 1.0f / lrun[mt * 16 + lq * 4 + r];
    for (int mt = 0; mt < 2; mt++)
      for (int nt = 0; nt < 8; nt++)
        for (int r = 0; r < 4; r++) {
          int row = q0 + mt * 16 + lq * 4 + r;
          int col = wv * 128 + nt * 16 + lm;
          out[(base + row) * (size_t)UDIM + col] = oacc[mt][nt][r] * linv[mt][r];
        }
  }
}

extern "C" void kernel_launch(void* const* d_in, const int* in_sizes, int n_in,
                              void* d_out, int out_size, void* d_ws, size_t ws_size,
                              hipStream_t stream) {
  const float* x  = (const float*)d_in[0];
  const float* Wq = (const float*)d_in[1];
  const float* Wk = (const float*)d_in[2];
  const float* Wv = (const float*)d_in[3];
  const float* bq = (const float*)d_in[4];
  const float* bk = (const float*)d_in[5];
  const float* bv = (const float*)d_in[6];
  float* out = (float*)d_out;

  char* ws = (char*)d_ws;
  const size_t XB_BYTES  = (size_t)BATCH * S_LEN * DDIM * 2;       // 16.8 MB
  const size_t WT_BYTES  = (size_t)3 * DDIM * UDIM * 2;            // 1.5 MB
  const size_t QKV_BYTES = (size_t)3 * BATCH * S_LEN * UDIM * 2;   // 50.3 MB
  f16* xb  = (f16*)ws;
  f16* WT  = (f16*)(ws + XB_BYTES);
  f16* QKV = (f16*)(ws + XB_BYTES + WT_BYTES);
  f16* VT  = (f16*)(ws + XB_BYTES + WT_BYTES + QKV_BYTES);

  int n = BATCH * S_LEN * DDIM;
  cast_f32_f16<<<n / (256 * 4), 256, 0, stream>>>(x, xb, n);
  transpose_w<<<dim3(16, 16, 3), 256, 0, stream>>>(Wq, Wk, Wv, WT);
  gemm_qkv<<<dim3(128, 4, 3), 256, 0, stream>>>(xb, WT, bq, bk, bv, QKV, VT);
  // attn: blockIdx.x = batch so linear id % 8 == batch -> XCD-local K/V in L2
  attn<<<dim3(BATCH, S_LEN / 32), 256, 0, stream>>>(
      QKV, QKV + (size_t)BATCH * S_LEN * UDIM, VT, out);
}

// Round 3
// 182.044 us; speedup vs baseline: 1.1683x; 1.0326x over previous
//
#include <hip/hip_runtime.h>

#define BATCH 8
#define S_LEN 2048
#define DDIM 512
#define UDIM 512
#define WIN_L 128
#define WIN_R 128
#define PP 296  // Pb pitch (f16): mult of 8 for 16B-aligned b128 reads, 148 words -> 8 distinct bank starts

typedef _Float16 f16;
typedef __attribute__((ext_vector_type(8))) _Float16 f16x8;
typedef __attribute__((ext_vector_type(4))) _Float16 f16x4;
typedef __attribute__((ext_vector_type(4))) float f32x4;

__device__ __forceinline__ void gload_lds16(const void* g, void* l) {
  __builtin_amdgcn_global_load_lds((const __attribute__((address_space(1))) void*)g,
                                   (__attribute__((address_space(3))) void*)l, 16, 0, 0);
}

// ---------------- cast x (fp32) -> f16 ----------------
__global__ void cast_f32_f16(const float* __restrict__ in, f16* __restrict__ out, int n) {
  int i = (blockIdx.x * blockDim.x + threadIdx.x) * 4;
  if (i < n) {
    float4 v = *(const float4*)(in + i);
    f16x4 o;
    o[0] = (f16)v.x; o[1] = (f16)v.y; o[2] = (f16)v.z; o[3] = (f16)v.w;
    *(f16x4*)(out + i) = o;
  }
}

// ---------------- transpose W [D][U] fp32 -> WT [U][D] f16 (3 matrices) ----------------
__global__ void transpose_w(const float* __restrict__ Wq, const float* __restrict__ Wk,
                            const float* __restrict__ Wv, f16* __restrict__ WT) {
  const float* W = blockIdx.z == 0 ? Wq : (blockIdx.z == 1 ? Wk : Wv);
  f16* WTz = WT + (size_t)blockIdx.z * DDIM * UDIM;
  __shared__ float t[32][33];
  int tx = threadIdx.x & 31, ty = threadIdx.x >> 5;  // 32 x 8
  int n0 = blockIdx.x * 32, k0 = blockIdx.y * 32;
  for (int i = 0; i < 4; i++) {
    int r = ty * 4 + i;
    t[r][tx] = W[(size_t)(k0 + r) * UDIM + n0 + tx];
  }
  __syncthreads();
  for (int i = 0; i < 4; i++) {
    int r = ty * 4 + i;
    WTz[(size_t)(n0 + r) * DDIM + k0 + tx] = (f16)t[tx][r];
  }
}

// ---------------- QKV GEMM: BK=64 as 2x BK=32 chunks (m97 layout preserved), 16 barriers ----------------
__global__ __launch_bounds__(256, 2) void gemm_qkv(
    const f16* __restrict__ X, const f16* __restrict__ WT,
    const float* __restrict__ bq, const float* __restrict__ bk, const float* __restrict__ bv,
    f16* __restrict__ QKV, f16* __restrict__ VT) {
  int z = blockIdx.z;
  const f16* WTz = WT + (size_t)z * DDIM * UDIM;   // [U][D] layout
  const float* bias = z == 0 ? bq : (z == 1 ? bk : bv);
  f16* out = QKV + (size_t)z * (BATCH * S_LEN) * UDIM;

  __shared__ f16 Al[2][128 * 32];
  __shared__ f16 Bl[2][128 * 32];

  int tid = threadIdx.x, wv = tid >> 6, ln = tid & 63;
  int m0 = blockIdx.x * 128, n0 = blockIdx.y * 128;
  int wm = (wv >> 1) * 64, wn = (wv & 1) * 64;
  int lm = ln & 15, lq = ln >> 4;
  int srow = ln >> 2, scol = (ln & 3) * 8;  // 16 rows x 32 cols per gload

  f32x4 acc[4][4];
  for (int mt = 0; mt < 4; mt++)
    for (int nt = 0; nt < 4; nt++)
      for (int r = 0; r < 4; r++) acc[mt][nt][r] = 0.f;

  for (int k0 = 0; k0 < DDIM; k0 += 64) {
    for (int half = 0; half < 2; half++) {
      int r0 = half * 64 + wv * 16;  // wave-uniform
      for (int c = 0; c < 2; c++) {
        gload_lds16(X + (size_t)(m0 + r0 + srow) * DDIM + k0 + c * 32 + scol, &Al[c][r0 * 32]);
        gload_lds16(WTz + (size_t)(n0 + r0 + srow) * DDIM + k0 + c * 32 + scol, &Bl[c][r0 * 32]);
      }
    }
    __syncthreads();
#pragma unroll
    for (int c = 0; c < 2; c++) {
      f16x8 af[4], bfr[4];
      for (int mt = 0; mt < 4; mt++) af[mt] = *(const f16x8*)&Al[c][(wm + mt * 16 + lm) * 32 + lq * 8];
      for (int nt = 0; nt < 4; nt++) bfr[nt] = *(const f16x8*)&Bl[c][(wn + nt * 16 + lm) * 32 + lq * 8];
      for (int mt = 0; mt < 4; mt++)
        for (int nt = 0; nt < 4; nt++)
          acc[mt][nt] = __builtin_amdgcn_mfma_f32_16x16x32_f16(af[mt], bfr[nt], acc[mt][nt], 0, 0, 0);
    }
    __syncthreads();
  }

  if (z == 2) {
    // transposed epilogue: VT[b][u][s], 4 consecutive s per lane -> 8B stores
    for (int mt = 0; mt < 4; mt++)
      for (int nt = 0; nt < 4; nt++) {
        int col = n0 + wn + nt * 16 + lm;          // u
        float bv_ = bias[col];
        int row0 = m0 + wm + mt * 16 + lq * 4;     // global s index (r=0)
        int bb = row0 >> 11, ss = row0 & 2047;
        f16x4 o;
        for (int r = 0; r < 4; r++) o[r] = (f16)(acc[mt][nt][r] + bv_);
        *(f16x4*)&VT[((size_t)bb * UDIM + col) * S_LEN + ss] = o;
      }
  } else {
    for (int mt = 0; mt < 4; mt++)
      for (int nt = 0; nt < 4; nt++) {
        int col = n0 + wn + nt * 16 + lm;
        float bv_ = bias[col];
        for (int r = 0; r < 4; r++) {
          int row = m0 + wm + mt * 16 + lq * 4 + r;
          out[(size_t)row * UDIM + col] = (f16)(acc[mt][nt][r] + bv_);
        }
      }
  }
}

// ---------------- single-pass sliding-window attention, v3 ----------------
// 32-row q-tile per block. Whole 288-key strip computed at once: S in registers
// (waves 2x2 over rows x cols), ONE softmax (no online rescale), P parked in LDS,
// one PV sweep. 2 barriers per block total. K/V read directly from L2 (XCD-pinned).
__global__ __launch_bounds__(256, 2) void attn(
    const f16* __restrict__ Q, const f16* __restrict__ K, const f16* __restrict__ VT,
    float* __restrict__ out) {
  __shared__ f16 Pb[32 * PP];          // P strip [32 rows][288 keys], f16
  __shared__ float wmax[2][32], wsum[2][32];

  int tid = threadIdx.x, wv = tid >> 6, ln = tid & 63;
  int lm = ln & 15, lq = ln >> 4;
  int b = blockIdx.x, q0 = blockIdx.y * 32;
  int rh = wv & 1, ch = wv >> 1;       // wave: rows rh*16..+16, S-cols ch*144..+144
  const size_t base = (size_t)b * S_LEN;
  const int strip0 = q0 - WIN_L;       // strip covers keys [strip0, strip0+288)

  // ---- Q fragments (A-operand, rows rh*16+lm), invariant ----
  f16x8 qf[16];
  {
    const f16* qrow = Q + (base + q0 + rh * 16 + lm) * (size_t)DDIM + lq * 8;
#pragma unroll
    for (int kk = 0; kk < 16; kk++) qf[kk] = *(const f16x8*)(qrow + kk * 32);
  }

  // ---- S phase: 9 col-tiles x 16 K-steps = 144 MFMAs, no barriers ----
  f32x4 sacc[9];
#pragma unroll
  for (int t = 0; t < 9; t++)
    for (int r = 0; r < 4; r++) sacc[t][r] = 0.f;
#pragma unroll
  for (int t = 0; t < 9; t++) {
    int key = strip0 + ch * 144 + t * 16 + lm;
    int kc = key < 0 ? 0 : (key > S_LEN - 1 ? S_LEN - 1 : key);  // clamp addr; masked below
    const f16* kp = K + (base + kc) * (size_t)DDIM + lq * 8;
#pragma unroll
    for (int kk = 0; kk < 16; kk++) {
      f16x8 bf = *(const f16x8*)(kp + kk * 32);
      sacc[t] = __builtin_amdgcn_mfma_f32_16x16x32_f16(qf[kk], bf, sacc[t], 0, 0, 0);
    }
  }

  // ---- scale + mask + in-register row max (cols live in lm lanes: shfl within quad) ----
  const float scale = 0.044194173824159216f;  // 1/sqrt(512)
  float mx[4] = {-1e30f, -1e30f, -1e30f, -1e30f};
#pragma unroll
  for (int t = 0; t < 9; t++) {
    int kj = strip0 + ch * 144 + t * 16 + lm;
#pragma unroll
    for (int r = 0; r < 4; r++) {
      int qi = q0 + rh * 16 + lq * 4 + r;
      float s = sacc[t][r] * scale;
      bool ok = (kj >= 0) && (kj < S_LEN) && (kj >= qi - WIN_L) && (kj <= qi + WIN_R);
      s = ok ? s : -1e30f;
      sacc[t][r] = s;
      mx[r] = fmaxf(mx[r], s);
    }
  }
#pragma unroll
  for (int r = 0; r < 4; r++) {
    mx[r] = fmaxf(mx[r], __shfl_xor(mx[r], 1));
    mx[r] = fmaxf(mx[r], __shfl_xor(mx[r], 2));
    mx[r] = fmaxf(mx[r], __shfl_xor(mx[r], 4));
    mx[r] = fmaxf(mx[r], __shfl_xor(mx[r], 8));
  }
  if (lm == 0) {
#pragma unroll
    for (int r = 0; r < 4; r++) wmax[ch][rh * 16 + lq * 4 + r] = mx[r];
  }
  __syncthreads();  // barrier 1: exchange per-col-half row maxima

  // ---- exp + row sums + park P in LDS ----
  float mrow[4], sum[4] = {0.f, 0.f, 0.f, 0.f};
#pragma unroll
  for (int r = 0; r < 4; r++) {
    int row = rh * 16 + lq * 4 + r;
    mrow[r] = fmaxf(wmax[0][row], wmax[1][row]);
  }
#pragma unroll
  for (int t = 0; t < 9; t++) {
#pragma unroll
    for (int r = 0; r < 4; r++) {
      float p = __expf(sacc[t][r] - mrow[r]);
      sum[r] += p;
      Pb[(rh * 16 + lq * 4 + r) * PP + ch * 144 + t * 16 + lm] = (f16)p;
    }
  }
#pragma unroll
  for (int r = 0; r < 4; r++) {
    sum[r] += __shfl_xor(sum[r], 1);
    sum[r] += __shfl_xor(sum[r], 2);
    sum[r] += __shfl_xor(sum[r], 4);
    sum[r] += __shfl_xor(sum[r], 8);
  }
  if (lm == 0) {
#pragma unroll
    for (int r = 0; r < 4; r++) wsum[ch][rh * 16 + lq * 4 + r] = sum[r];
  }
  __syncthreads();  // barrier 2: P + sums visible

  // ---- PV sweep: O[32 x 128-u-slice] = P[32x288] * V[288 x u]; 144 MFMAs, no barriers ----
  f32x4 oacc[2][8];
#pragma unroll
  for (int mt = 0; mt < 2; mt++)
    for (int nt = 0; nt < 8; nt++)
      for (int r = 0; r < 4; r++) oacc[mt][nt][r] = 0.f;

  const f16* vbase = VT + ((size_t)b * UDIM + wv * 128 + lm) * S_LEN;
#pragma unroll
  for (int kst = 0; kst < 9; kst++) {
    f16x8 pf0 = *(const f16x8*)&Pb[lm * PP + kst * 32 + lq * 8];
    f16x8 pf1 = *(const f16x8*)&Pb[(16 + lm) * PP + kst * 32 + lq * 8];
    int key = strip0 + kst * 32 + lq * 8;
    int kc = key < 0 ? 0 : (key > S_LEN - 8 ? S_LEN - 8 : key);  // aligned clamp; P=0 where masked
#pragma unroll
    for (int nt = 0; nt < 8; nt++) {
      f16x8 vb = *(const f16x8*)(vbase + (size_t)nt * 16 * S_LEN + kc);
      oacc[0][nt] = __builtin_amdgcn_mfma_f32_16x16x32_f16(pf0, vb, oacc[0][nt], 0, 0, 0);
      oacc[1][nt] = __builtin_amdgcn_mfma_f32_16x16x32_f16(pf1, vb, oacc[1][nt], 0, 0, 0);
    }
  }

  // ---- epilogue: O /= l, fp32 store ----
  float linv[2][4];
#pragma unroll
  for (int mt = 0; mt < 2; mt++)
    for (int r = 0; r < 4; r++) {
      int row = mt * 16 + lq * 4 + r;
      linv[mt][r] = 1.0f / (wsum[0][row] + wsum[1][row]);
    }
#pragma unroll
  for (int mt = 0; mt < 2; mt++)
    for (int nt = 0; nt < 8; nt++)
      for (int r = 0; r < 4; r++) {
        int row = q0 + mt * 16 + lq * 4 + r;
        int col = wv * 128 + nt * 16 + lm;
        out[(base + row) * (size_t)UDIM + col] = oacc[mt][nt][r] * linv[mt][r];
      }
}

extern "C" void kernel_launch(void* const* d_in, const int* in_sizes, int n_in,
                              void* d_out, int out_size, void* d_ws, size_t ws_size,
                              hipStream_t stream) {
  const float* x  = (const float*)d_in[0];
  const float* Wq = (const float*)d_in[1];
  const float* Wk = (const float*)d_in[2];
  const float* Wv = (const float*)d_in[3];
  const float* bq = (const float*)d_in[4];
  const float* bk = (const float*)d_in[5];
  const float* bv = (const float*)d_in[6];
  float* out = (float*)d_out;

  char* ws = (char*)d_ws;
  const size_t XB_BYTES  = (size_t)BATCH * S_LEN * DDIM * 2;       // 16.8 MB
  const size_t WT_BYTES  = (size_t)3 * DDIM * UDIM * 2;            // 1.5 MB
  const size_t QKV_BYTES = (size_t)3 * BATCH * S_LEN * UDIM * 2;   // 50.3 MB
  f16* xb  = (f16*)ws;
  f16* WT  = (f16*)(ws + XB_BYTES);
  f16* QKV = (f16*)(ws + XB_BYTES + WT_BYTES);
  f16* VT  = (f16*)(ws + XB_BYTES + WT_BYTES + QKV_BYTES);

  int n = BATCH * S_LEN * DDIM;
  cast_f32_f16<<<n / (256 * 4), 256, 0, stream>>>(x, xb, n);
  transpose_w<<<dim3(16, 16, 3), 256, 0, stream>>>(Wq, Wk, Wv, WT);
  gemm_qkv<<<dim3(128, 4, 3), 256, 0, stream>>>(xb, WT, bq, bk, bv, QKV, VT);
  // attn: blockIdx.x = batch so linear id % 8 == batch -> XCD-local K/V in L2
  attn<<<dim3(BATCH, S_LEN / 32), 256, 0, stream>>>(
      QKV, QKV + (size_t)BATCH * S_LEN * UDIM, VT, out);
}